// Round 2
// baseline (3011.640 us; speedup 1.0000x reference)
//
#include <hip/hip_runtime.h>
#include <hip/hip_bf16.h>
#include <stdint.h>

// Problem constants
#define NB 64        // batch
#define HD 512       // hidden = embed
#define SD 128       // src len
#define VC 32000     // vocab
#define NSTEP 32     // T-1
#define NKS 6        // K-split for gates GEMM (chunks of 256, never cross source boundaries)

typedef __attribute__((ext_vector_type(8))) short s16x8;
typedef __attribute__((ext_vector_type(4))) float fx4;

// ---- workspace layout (bytes). total ~40.2 MB ----
static constexpr size_t OFF_H    = 0;                        // f32 [64][512]
static constexpr size_t OFF_C    = OFF_H    + 131072ull*4;   // f32 [64][512]
static constexpr size_t OFF_GP   = OFF_C    + 131072ull*4;   // f32 [6][64][2048]
static constexpr size_t OFF_OTP  = OFF_GP   + 786432ull*4;   // f32 (unused now, kept for layout)
static constexpr size_t OFF_MASK = OFF_OTP  + 196608ull*4;   // f32 [64][128]
static constexpr size_t OFF_BS   = OFF_MASK + 8192ull*4;     // f32 [2048] b_ih+b_hh
static constexpr size_t OFF_WCAT = OFF_BS   + 2048ull*4;     // bf16 [2048][1536]  (dead after scan -> W_out bf16)
static constexpr size_t OFF_WV   = OFF_WCAT + 3145728ull*2;  // bf16 [512][1536]
static constexpr size_t OFF_EHB  = OFF_WV   + 786432ull*2;   // bf16 [64][128][1024]
static constexpr size_t OFF_ENCP = OFF_EHB  + 8388608ull*2;  // bf16 [8192][512]
static constexpr size_t OFF_YB   = OFF_ENCP + 4194304ull*2;  // bf16 [32][64][512]
static constexpr size_t OFF_ACAT = OFF_YB   + 1048576ull*2;  // bf16 [64][1536] = [y|o|h]
static constexpr size_t OFF_U    = OFF_ACAT + 98304ull*2;    // bf16 [64][1536] = [a|h]
static constexpr size_t OFF_OB   = OFF_U    + 98304ull*2;    // bf16 [32][64][512]

__device__ __forceinline__ float bf2f(short s) {
  return __uint_as_float(((unsigned)(unsigned short)s) << 16);
}
__device__ __forceinline__ short f2bf(float f) {  // round-to-nearest-even
  unsigned u = __float_as_uint(f);
  return (short)((u + 0x7fffu + ((u >> 16) & 1u)) >> 16);
}
// LDS XOR swizzle on 16B chunks: worst-case 2-way conflicts (free per m136)
__device__ __forceinline__ int swz(int row, int chunk) {
  return row * 32 + ((chunk ^ ((row >> 1) & 3)) * 8);  // offset in shorts
}

// ---------- one-time casts / gathers / inits (+ mask canonicalization in block 0) ----------
__global__ void k_setup(const int* tgt, const float* ench, const float* dih, const float* dic,
                        const float* embed, const float* W_ih, const float* W_hh,
                        const float* b_ih, const float* b_hh, const float* W_v,
                        const unsigned char* mraw, char* ws) {
  if (blockIdx.x == 0) {  // mask: detect bool(1B) vs int32 layout, write f32 mask
    __shared__ int flag;
    if (threadIdx.x == 0) flag = 0;
    __syncthreads();
    int any = 0;
    for (int i = threadIdx.x; i < 8192; i += 256)
      if ((i & 3) && mraw[i]) any = 1;   // int32 {0,1} never has nonzero at byte_off%4!=0
    if (any) atomicOr(&flag, 1);
    __syncthreads();
    const bool isBool = (flag != 0);
    const int* mi = (const int*)mraw;
    float* maskF = (float*)(ws + OFF_MASK);
    for (int i = threadIdx.x; i < 8192; i += 256)
      maskF[i] = isBool ? (float)(mraw[i] != 0) : (float)(mi[i] != 0);
  }
  const unsigned N0 = 3145728u;        // Wcat
  const unsigned N1 = N0 + 786432u;    // Wv
  const unsigned N2 = N1 + 8388608u;   // EHb
  const unsigned N3 = N2 + 1048576u;   // Yb
  const unsigned N4 = N3 + 2048u;      // bsum
  const unsigned N5 = N4 + 32768u;     // state init
  short* Wcat = (short*)(ws + OFF_WCAT);
  short* Wv   = (short*)(ws + OFF_WV);
  short* EHb  = (short*)(ws + OFF_EHB);
  short* Yb   = (short*)(ws + OFF_YB);
  float* bsum = (float*)(ws + OFF_BS);
  float* h    = (float*)(ws + OFF_H);
  float* c    = (float*)(ws + OFF_C);
  short* acat = (short*)(ws + OFF_ACAT);
  for (unsigned i = blockIdx.x * 256u + threadIdx.x; i < N5; i += gridDim.x * 256u) {
    if (i < N0) {
      unsigned r = i / 1536u, k = i % 1536u;
      float v = (k < 1024u) ? W_ih[(size_t)r * 1024 + k] : W_hh[(size_t)r * 512 + (k - 1024u)];
      Wcat[i] = f2bf(v);
    } else if (i < N1) {
      unsigned j = i - N0; Wv[j] = f2bf(W_v[j]);
    } else if (i < N2) {
      unsigned j = i - N1; EHb[j] = f2bf(ench[j]);
    } else if (i < N3) {
      unsigned j = i - N2;                       // t*32768 + b*512 + e
      unsigned tt = j >> 15, rem = j & 32767u, bb = rem >> 9, e = rem & 511u;
      int row = tgt[tt * 64 + bb];
      Yb[j] = f2bf(embed[(size_t)row * 512 + e]);
    } else if (i < N4) {
      unsigned j = i - N3; bsum[j] = b_ih[j] + b_hh[j];
    } else {
      unsigned j = i - N4;                       // b*512 + jj
      unsigned bb = j >> 9, jj = j & 511u;
      float hv = dih[j], cv = dic[j];
      h[j] = hv; c[j] = cv;
      acat[bb * 1536 + 1024 + jj] = f2bf(hv);    // h part
      acat[bb * 1536 + 512 + jj]  = 0;           // o_prev = 0
      int row0 = tgt[bb];                        // t = 0 token
      acat[bb * 1536 + jj] = f2bf(embed[(size_t)row0 * 512 + jj]);
    }
  }
}

// ---------- cast W_out f32 -> bf16 into the (dead-after-scan) WCAT region ----------
__global__ __launch_bounds__(256) void k_castw(const float* __restrict__ W, short* __restrict__ out) {
  size_t i0 = ((size_t)blockIdx.x * 256 + threadIdx.x) * 8;  // grid 8000 * 256 * 8 = 16,384,000
  const float4* p = (const float4*)(W + i0);
  float4 a = p[0], b = p[1];
  s16x8 v;
  v[0] = f2bf(a.x); v[1] = f2bf(a.y); v[2] = f2bf(a.z); v[3] = f2bf(a.w);
  v[4] = f2bf(b.x); v[5] = f2bf(b.y); v[6] = f2bf(b.z); v[7] = f2bf(b.w);
  *(s16x8*)(out + i0) = v;
}

// ---------- 128x128 bf16-MFMA GEMM: C[M][N] = A(bf16,MxK) * B(NxK)^T ----------
template<bool B_F32, bool C_BF16>
__global__ __launch_bounds__(256) void k_gemm128(const short* __restrict__ A,
                                                 const void* __restrict__ Bp,
                                                 void* __restrict__ Cp, int K, int ldc) {
  __shared__ short As[128 * 32];
  __shared__ short Bs[128 * 32];
  const int tid = threadIdx.x, wid = tid >> 6, lane = tid & 63;
  const int wm = wid >> 1, wn = wid & 1;
  const int m0 = blockIdx.x * 128, n0 = blockIdx.y * 128;
  const int srow = tid >> 1, shalf = tid & 1;   // 128 rows x 2 halves of 16
  fx4 acc[4][4] = {};
  for (int k0 = 0; k0 < K; k0 += 32) {
    {
      const s16x8* ga = (const s16x8*)(A + (size_t)(m0 + srow) * K + k0 + shalf * 16);
      s16x8 va0 = ga[0], va1 = ga[1];
      s16x8 vb0, vb1;
      if (B_F32) {
        const float4* gb = (const float4*)((const float*)Bp + (size_t)(n0 + srow) * K + k0 + shalf * 16);
        float4 b0 = gb[0], b1 = gb[1], b2 = gb[2], b3 = gb[3];
        vb0[0]=f2bf(b0.x); vb0[1]=f2bf(b0.y); vb0[2]=f2bf(b0.z); vb0[3]=f2bf(b0.w);
        vb0[4]=f2bf(b1.x); vb0[5]=f2bf(b1.y); vb0[6]=f2bf(b1.z); vb0[7]=f2bf(b1.w);
        vb1[0]=f2bf(b2.x); vb1[1]=f2bf(b2.y); vb1[2]=f2bf(b2.z); vb1[3]=f2bf(b2.w);
        vb1[4]=f2bf(b3.x); vb1[5]=f2bf(b3.y); vb1[6]=f2bf(b3.z); vb1[7]=f2bf(b3.w);
      } else {
        const s16x8* gb = (const s16x8*)((const short*)Bp + (size_t)(n0 + srow) * K + k0 + shalf * 16);
        vb0 = gb[0]; vb1 = gb[1];
      }
      *(s16x8*)&As[swz(srow, shalf * 2)]     = va0;
      *(s16x8*)&As[swz(srow, shalf * 2 + 1)] = va1;
      *(s16x8*)&Bs[swz(srow, shalf * 2)]     = vb0;
      *(s16x8*)&Bs[swz(srow, shalf * 2 + 1)] = vb1;
    }
    __syncthreads();
    const int q = lane >> 4, r16 = lane & 15;
    s16x8 af[4], bfr[4];
#pragma unroll
    for (int i = 0; i < 4; ++i) {
      int ra = wm * 64 + i * 16 + r16;
      int rb = wn * 64 + i * 16 + r16;
      af[i]  = *(const s16x8*)&As[swz(ra, q)];
      bfr[i] = *(const s16x8*)&Bs[swz(rb, q)];
    }
#pragma unroll
    for (int i = 0; i < 4; ++i)
#pragma unroll
      for (int j = 0; j < 4; ++j)
        acc[i][j] = __builtin_amdgcn_mfma_f32_16x16x32_bf16(af[i], bfr[j], acc[i][j], 0, 0, 0);
    __syncthreads();
  }
  const int q = lane >> 4, r16 = lane & 15;
#pragma unroll
  for (int i = 0; i < 4; ++i)
#pragma unroll
    for (int j = 0; j < 4; ++j)
#pragma unroll
      for (int r = 0; r < 4; ++r) {
        int row = m0 + wm * 64 + i * 16 + q * 4 + r;
        int col = n0 + wn * 64 + j * 16 + r16;
        float v = acc[i][j][r];
        if (C_BF16) ((short*)Cp)[(size_t)row * ldc + col] = f2bf(v);
        else        ((float*)Cp)[(size_t)row * ldc + col] = v;
      }
}

// ---------- 64x64 partial GEMM (K-split): GP[ks][64][2048] = acat * Wcat^T chunk ks ----------
__global__ __launch_bounds__(256) void k_part(const short* __restrict__ A,
                                              const short* __restrict__ B,
                                              float* __restrict__ Pp, int N) {
  __shared__ short As[64 * 32];
  __shared__ short Bs[64 * 32];
  const int tid = threadIdx.x, wid = tid >> 6, lane = tid & 63;
  const int ct = blockIdx.x, ks = blockIdx.y;
  const int n0 = ct * 64;
  const int srow = tid >> 2, schunk = tid & 3;  // 64 rows x 4 chunks of 8
  fx4 acc[4] = {};
  for (int kt = 0; kt < 8; ++kt) {
    int k0 = ks * 256 + kt * 32;
    *(s16x8*)&As[swz(srow, schunk)] = *(const s16x8*)(A + (size_t)srow * 1536 + k0 + schunk * 8);
    *(s16x8*)&Bs[swz(srow, schunk)] = *(const s16x8*)(B + (size_t)(n0 + srow) * 1536 + k0 + schunk * 8);
    __syncthreads();
    const int q = lane >> 4, r16 = lane & 15;
    s16x8 bfrag = *(const s16x8*)&Bs[swz(wid * 16 + r16, q)];
#pragma unroll
    for (int f = 0; f < 4; ++f) {
      s16x8 afrag = *(const s16x8*)&As[swz(f * 16 + r16, q)];
      acc[f] = __builtin_amdgcn_mfma_f32_16x16x32_bf16(afrag, bfrag, acc[f], 0, 0, 0);
    }
    __syncthreads();
  }
  const int q = lane >> 4, r16 = lane & 15;
  float* out = Pp + (size_t)ks * 64 * N;
#pragma unroll
  for (int f = 0; f < 4; ++f)
#pragma unroll
    for (int r = 0; r < 4; ++r) {
      int m = f * 16 + q * 4 + r;
      out[(size_t)m * N + n0 + wid * 16 + r16] = acc[f][r];
    }
}

// ---------- fused: reduce gate partials -> LSTM cell -> attention -> write u=[a|h] ----------
__global__ __launch_bounds__(256) void k_cellattn(char* ws) {
  const int b = blockIdx.x, tid = threadIdx.x;
  float* h = (float*)(ws + OFF_H);
  float* c = (float*)(ws + OFF_C);
  const float* gp = (const float*)(ws + OFF_GP);
  const float* bs = (const float*)(ws + OFF_BS);
  const float* mf = (const float*)(ws + OFF_MASK);
  const short* encp = (const short*)(ws + OFF_ENCP);
  const short* ehb  = (const short*)(ws + OFF_EHB);
  short* acat = (short*)(ws + OFF_ACAT);
  short* u    = (short*)(ws + OFF_U);

  __shared__ float hs[512];
  __shared__ float es[128];
  __shared__ float ps[256];
  __shared__ float red[2];

  // LSTM cell (reduce 6 K-split partials, 4 gates each)
  for (int j = tid; j < 512; j += 256) {
    float g0 = bs[j], g1 = bs[j + 512], g2 = bs[j + 1024], g3 = bs[j + 1536];
#pragma unroll
    for (int kspl = 0; kspl < NKS; ++kspl) {
      const float* p = gp + (size_t)kspl * 64 * 2048 + b * 2048;
      g0 += p[j]; g1 += p[j + 512]; g2 += p[j + 1024]; g3 += p[j + 1536];
    }
    float ig = 1.f / (1.f + __expf(-g0));
    float fg = 1.f / (1.f + __expf(-g1));
    float gg = tanhf(g2);
    float og = 1.f / (1.f + __expf(-g3));
    float cc = fg * c[b * 512 + j] + ig * gg;
    float hh = og * tanhf(cc);
    c[b * 512 + j] = cc;
    h[b * 512 + j] = hh;
    hs[j] = hh;
    short hb = f2bf(hh);
    acat[b * 1536 + 1024 + j] = hb;
    u[b * 1536 + 1024 + j] = hb;
  }
  __syncthreads();
  // e_t: 128 positions x 2 threads (256-wide half dot each), 4 accumulators to break dep chain
  {
    int s = tid >> 1, half = tid & 1;
    const short* er = encp + ((size_t)b * 128 + s) * 512 + half * 256;
    const float* hp = hs + half * 256;
    float a0 = 0.f, a1 = 0.f, a2 = 0.f, a3 = 0.f;
    for (int k = 0; k < 256; k += 32) {
      s16x8 v0 = *(const s16x8*)(er + k);
      s16x8 v1 = *(const s16x8*)(er + k + 8);
      s16x8 v2 = *(const s16x8*)(er + k + 16);
      s16x8 v3 = *(const s16x8*)(er + k + 24);
#pragma unroll
      for (int jj = 0; jj < 8; ++jj) {
        a0 += bf2f(v0[jj]) * hp[k + jj];
        a1 += bf2f(v1[jj]) * hp[k + 8 + jj];
        a2 += bf2f(v2[jj]) * hp[k + 16 + jj];
        a3 += bf2f(v3[jj]) * hp[k + 24 + jj];
      }
    }
    ps[tid] = (a0 + a1) + (a2 + a3);
  }
  __syncthreads();
  if (tid < 128) {
    float e = ps[2 * tid] + ps[2 * tid + 1];
    if (mf[b * 128 + tid] > 0.5f) e = -1e30f;
    es[tid] = e;
  }
  __syncthreads();
  if (tid < 64) {
    float m = fmaxf(es[tid], es[tid + 64]);
    for (int off = 32; off; off >>= 1) m = fmaxf(m, __shfl_xor(m, off));
    if (tid == 0) red[0] = m;
  }
  __syncthreads();
  float m = red[0];
  if (tid < 128) es[tid] = __expf(es[tid] - m);
  __syncthreads();
  if (tid < 64) {
    float s = es[tid] + es[tid + 64];
    for (int off = 32; off; off >>= 1) s += __shfl_xor(s, off);
    if (tid == 0) red[1] = s;
  }
  __syncthreads();
  float inv = 1.f / red[1];
  if (tid < 128) es[tid] *= inv;   // alpha
  __syncthreads();
  // a_t[k] = sum_s alpha[s] * enc_hidden[b][s][k], 4 accumulators
  for (int it = 0; it < 4; ++it) {
    int k = it * 256 + tid;
    const short* col = ehb + (size_t)b * 128 * 1024 + k;
    float a0 = 0.f, a1 = 0.f, a2 = 0.f, a3 = 0.f;
    for (int s = 0; s < 128; s += 4) {
      a0 += es[s]     * bf2f(col[(size_t)s * 1024]);
      a1 += es[s + 1] * bf2f(col[(size_t)(s + 1) * 1024]);
      a2 += es[s + 2] * bf2f(col[(size_t)(s + 2) * 1024]);
      a3 += es[s + 3] * bf2f(col[(size_t)(s + 3) * 1024]);
    }
    u[b * 1536 + k] = f2bf((a0 + a1) + (a2 + a3));
  }
}

// ---------- fused u-GEMM + tanh + state update: o_t = tanh(u @ W_v^T); OB[t]=o; acat.o=o; acat.y=Y[t+1] ----------
__global__ __launch_bounds__(256) void k_uot(char* ws, int t) {
  __shared__ short As[64 * 32];
  __shared__ short Bs[64 * 32];
  const int tid = threadIdx.x, wid = tid >> 6, lane = tid & 63;
  const int ct = blockIdx.x, n0 = ct * 64;
  const short* A = (const short*)(ws + OFF_U);
  const short* B = (const short*)(ws + OFF_WV);
  const int srow = tid >> 2, schunk = tid & 3;
  fx4 acc[4] = {};
  for (int kt = 0; kt < 48; ++kt) {
    int k0 = kt * 32;
    *(s16x8*)&As[swz(srow, schunk)] = *(const s16x8*)(A + (size_t)srow * 1536 + k0 + schunk * 8);
    *(s16x8*)&Bs[swz(srow, schunk)] = *(const s16x8*)(B + (size_t)(n0 + srow) * 1536 + k0 + schunk * 8);
    __syncthreads();
    const int q = lane >> 4, r16 = lane & 15;
    s16x8 bfrag = *(const s16x8*)&Bs[swz(wid * 16 + r16, q)];
#pragma unroll
    for (int f = 0; f < 4; ++f) {
      s16x8 afrag = *(const s16x8*)&As[swz(f * 16 + r16, q)];
      acc[f] = __builtin_amdgcn_mfma_f32_16x16x32_bf16(afrag, bfrag, acc[f], 0, 0, 0);
    }
    __syncthreads();
  }
  short* OB   = (short*)(ws + OFF_OB);
  short* acat = (short*)(ws + OFF_ACAT);
  const int q = lane >> 4, r16 = lane & 15;
#pragma unroll
  for (int f = 0; f < 4; ++f)
#pragma unroll
    for (int r = 0; r < 4; ++r) {
      int m = f * 16 + q * 4 + r, n = n0 + wid * 16 + r16;
      short ob = f2bf(tanhf(acc[f][r]));
      OB[(size_t)t * 32768 + m * 512 + n] = ob;
      acat[m * 1536 + 512 + n] = ob;             // o_prev for next step
    }
  if (t < 31) {                                  // next token embedding into acat.y
    const short* yb = (const short*)(ws + OFF_YB);
    for (int idx = tid; idx < 4096; idx += 256) {
      int m = idx >> 6, nn = idx & 63;
      acat[m * 1536 + n0 + nn] = yb[(size_t)(t + 1) * 32768 + m * 512 + n0 + nn];
    }
  }
}

extern "C" void kernel_launch(void* const* d_in, const int* in_sizes, int n_in,
                              void* d_out, int out_size, void* d_ws, size_t ws_size,
                              hipStream_t stream) {
  const int*   tgt   = (const int*)d_in[0];
  const float* ench  = (const float*)d_in[1];
  const float* dih   = (const float*)d_in[2];
  const float* dic   = (const float*)d_in[3];
  const unsigned char* mask = (const unsigned char*)d_in[4];
  const float* embed = (const float*)d_in[5];
  const float* W_ih  = (const float*)d_in[6];
  const float* W_hh  = (const float*)d_in[7];
  const float* b_ih  = (const float*)d_in[8];
  const float* b_hh  = (const float*)d_in[9];
  const float* W_att = (const float*)d_in[10];
  const float* W_v   = (const float*)d_in[11];
  const float* W_out = (const float*)d_in[12];
  char* ws = (char*)d_ws;

  hipLaunchKernelGGL(k_setup, dim3(8192), dim3(256), 0, stream,
                     tgt, ench, dih, dic, embed, W_ih, W_hh, b_ih, b_hh, W_v, mask, ws);
  // enc_proj: [8192x1024] x [512x1024]^T -> bf16 [8192][512]
  hipLaunchKernelGGL((k_gemm128<true, true>), dim3(64, 4), dim3(256), 0, stream,
                     (const short*)(ws + OFF_EHB), (const void*)W_att, (void*)(ws + OFF_ENCP), 1024, 512);
  for (int t = 0; t < NSTEP; ++t) {
    hipLaunchKernelGGL(k_part, dim3(32, NKS), dim3(256), 0, stream,
                       (const short*)(ws + OFF_ACAT), (const short*)(ws + OFF_WCAT),
                       (float*)(ws + OFF_GP), 2048);
    hipLaunchKernelGGL(k_cellattn, dim3(64), dim3(256), 0, stream, ws);
    hipLaunchKernelGGL(k_uot, dim3(8), dim3(256), 0, stream, ws, t);
  }
  // W_out -> bf16 into dead scan scratch, then P = O[2048x512] x W_out_bf16[32000x512]^T -> f32 d_out
  hipLaunchKernelGGL(k_castw, dim3(8000), dim3(256), 0, stream, W_out, (short*)(ws + OFF_WCAT));
  hipLaunchKernelGGL((k_gemm128<false, false>), dim3(16, 250), dim3(256), 0, stream,
                     (const short*)(ws + OFF_OB), (const void*)(ws + OFF_WCAT), d_out, 512, 32000);
}